// Round 3
// baseline (549.885 us; speedup 1.0000x reference)
//
#include <hip/hip_runtime.h>
#include <math.h>

#define N_NODE 100000
#define DEPTH  10
#define N_EDGE 1600000
#define D_FEAT 32
#define D_OUT  ((DEPTH + 1) * D_FEAT)   // 352 floats per node in output
#define NB_SCAN ((N_NODE + 255) / 256)  // 391 scan blocks

// ---------------------------------------------------------------------------
// bf16 helpers (bit-level, RTN-even)
// ---------------------------------------------------------------------------
__device__ inline unsigned short f32_to_bf16(float f) {
    unsigned int b = __float_as_uint(f);
    unsigned int r = (b + 0x7FFFu + ((b >> 16) & 1u)) >> 16;
    return (unsigned short)r;
}
__device__ inline float bf16_to_f32(unsigned short u) {
    return __uint_as_float(((unsigned int)u) << 16);
}

// ---------------------------------------------------------------------------
// Phase 1: degree count (in-degree over `row`)
// ---------------------------------------------------------------------------
__global__ void count_kernel(const int* __restrict__ row, int* __restrict__ cnt, int E) {
    int e = blockIdx.x * blockDim.x + threadIdx.x;
    if (e < E) atomicAdd(&cnt[row[e]], 1);
}

// ---------------------------------------------------------------------------
// Phase 2: hierarchical exclusive scan (3 kernels)
// ---------------------------------------------------------------------------
__device__ inline int wave_incl_scan(int v) {
    int lane = threadIdx.x & 63;
    #pragma unroll
    for (int off = 1; off < 64; off <<= 1) {
        int t = __shfl_up(v, off, 64);
        if (lane >= off) v += t;
    }
    return v;
}

__global__ void blockscan_kernel(const int* __restrict__ cnt, int* __restrict__ rowStart,
                                 int* __restrict__ blockSums, int n) {
    __shared__ int partials[4];
    int i = blockIdx.x * 256 + threadIdx.x;
    int v = (i < n) ? cnt[i] : 0;
    int incl = wave_incl_scan(v);
    int wid = threadIdx.x >> 6, lane = threadIdx.x & 63;
    if (lane == 63) partials[wid] = incl;
    __syncthreads();
    int woff = 0;
    #pragma unroll
    for (int w = 0; w < 4; ++w) woff += (w < wid) ? partials[w] : 0;
    if (i < n) rowStart[i] = woff + incl - v;               // block-local exclusive
    if (threadIdx.x == 255) blockSums[blockIdx.x] = woff + incl;
}

__global__ void scansums_kernel(int* __restrict__ blockSums, int nb) {
    __shared__ int partials[8];
    int i = threadIdx.x;                                    // 512 threads
    int v = (i < nb) ? blockSums[i] : 0;
    int incl = wave_incl_scan(v);
    int wid = i >> 6, lane = i & 63;
    if (lane == 63) partials[wid] = incl;
    __syncthreads();
    int woff = 0;
    #pragma unroll
    for (int w = 0; w < 8; ++w) woff += (w < wid) ? partials[w] : 0;
    if (i < nb) blockSums[i] = woff + incl - v;             // exclusive
    if (i == 511) blockSums[nb] = woff + incl;              // grand total
}

__global__ void addoffs_kernel(int* __restrict__ rowStart, const int* __restrict__ blockSums,
                               int n, int nb) {
    int i = blockIdx.x * 256 + threadIdx.x;
    if (i < n)  rowStart[i] += blockSums[i >> 8];
    if (i == n) rowStart[n] = blockSums[nb];
}

// ---------------------------------------------------------------------------
// Phase 3: dinv = (deg<0.5 ? deg+1 : deg)^-0.5
// ---------------------------------------------------------------------------
__global__ void dinv_kernel(const int* __restrict__ cnt, float* __restrict__ dinv, int n) {
    int i = blockIdx.x * blockDim.x + threadIdx.x;
    if (i < n) {
        float d = (float)cnt[i];
        if (d < 0.5f) d += 1.0f;
        dinv[i] = 1.0f / sqrtf(d);
    }
}

// ---------------------------------------------------------------------------
// Phase 4: scatter edges to CSR as combined 8B {col, val} entries.
// ---------------------------------------------------------------------------
__global__ void scatter_kernel(const int* __restrict__ row, const int* __restrict__ col,
                               const float* __restrict__ eattr,
                               const int* __restrict__ rowStart, int* __restrict__ cnt,
                               const float* __restrict__ dinv,
                               int2* __restrict__ csr, int E) {
    int e = blockIdx.x * blockDim.x + threadIdx.x;
    if (e < E) {
        int r = row[e], c = col[e];
        int p = rowStart[r] + atomicSub(&cnt[r], 1) - 1;
        float val = dinv[r] * eattr[e] * dinv[c];
        csr[p] = make_int2(c, __float_as_int(val));
    }
}

// ---------------------------------------------------------------------------
// alphas_t[L] = tanh(alphas[L]) (BASE_ALPHA = 1)
// ---------------------------------------------------------------------------
__global__ void alpha_kernel(const float* __restrict__ alphas, float* __restrict__ alphaT) {
    int i = threadIdx.x;
    if (i <= DEPTH) alphaT[i] = tanhf(alphas[i]);
}

// ---------------------------------------------------------------------------
// x_0: out[node,0,:] = x (fp32) and h0[node,:] = bf16(x)
// one thread per float4 (N_NODE*8)
// ---------------------------------------------------------------------------
__global__ void copyx_kernel(const float4* __restrict__ x4, float4* __restrict__ out4,
                             ushort4* __restrict__ h0) {
    int i = blockIdx.x * blockDim.x + threadIdx.x;
    if (i < N_NODE * 8) {
        int node = i >> 3, q = i & 7;
        float4 v = x4[i];
        out4[(size_t)node * 88 + q] = v;
        h0[i] = make_ushort4(f32_to_bf16(v.x), f32_to_bf16(v.y),
                             f32_to_bf16(v.z), f32_to_bf16(v.w));
    }
}

// ---------------------------------------------------------------------------
// Phase 5 (x10): SpMM level L, bf16 gather. ONE WAVE PER ROW.
// lane = (s,q): s = edge slot (0..7), q = feat quad (0..7).
// Gather: 8 lanes x ushort4 (8B) = 64B = one cache line per edge.
// Writes fp32 slice to out and bf16 row to h_cur (for next level).
// ---------------------------------------------------------------------------
__global__ __launch_bounds__(256) void spmm_kernel(const int* __restrict__ rowStart,
                                                   const int2* __restrict__ csr,
                                                   const float* __restrict__ alphaT,
                                                   int L,
                                                   const ushort4* __restrict__ h_prev,
                                                   ushort4* __restrict__ h_cur,
                                                   float* __restrict__ out) {
    int rowid = (int)((blockIdx.x * 256 + threadIdx.x) >> 6);
    if (rowid >= N_NODE) return;
    int lane = threadIdx.x & 63;
    int s = lane >> 3;                 // edge slot
    int q = lane & 7;                  // feat quad

    int start = rowStart[rowid];
    int end   = rowStart[rowid + 1];

    float4 acc = make_float4(0.f, 0.f, 0.f, 0.f);
    for (int e = start + s; e < end; e += 8) {
        int2    cv = csr[e];
        float   v  = __int_as_float(cv.y);
        ushort4 h  = h_prev[(size_t)cv.x * 8 + q];
        acc.x += v * bf16_to_f32(h.x);
        acc.y += v * bf16_to_f32(h.y);
        acc.z += v * bf16_to_f32(h.z);
        acc.w += v * bf16_to_f32(h.w);
    }

    // reduce across the 8 edge slots (lane-xor 8,16,32)
    #pragma unroll
    for (int m = 8; m < 64; m <<= 1) {
        acc.x += __shfl_xor(acc.x, m, 64);
        acc.y += __shfl_xor(acc.y, m, 64);
        acc.z += __shfl_xor(acc.z, m, 64);
        acc.w += __shfl_xor(acc.w, m, 64);
    }

    if (s == 0) {
        float a = alphaT[L];
        float4 r = make_float4(a * acc.x, a * acc.y, a * acc.z, a * acc.w);
        ((float4*)out)[(size_t)rowid * 88 + L * 8 + q] = r;
        if (L < DEPTH) {
            h_cur[(size_t)rowid * 8 + q] =
                make_ushort4(f32_to_bf16(r.x), f32_to_bf16(r.y),
                             f32_to_bf16(r.z), f32_to_bf16(r.w));
        }
    }
}

// ---------------------------------------------------------------------------
extern "C" void kernel_launch(void* const* d_in, const int* in_sizes, int n_in,
                              void* d_out, int out_size, void* d_ws, size_t ws_size,
                              hipStream_t stream) {
    const float* x      = (const float*)d_in[0];
    const int*   eidx   = (const int*)d_in[1];     // (2, E): row = [0,E), col = [E,2E)
    const float* eattr  = (const float*)d_in[2];
    const float* alphas = (const float*)d_in[3];
    float* out = (float*)d_out;

    const int* row = eidx;
    const int* col = eidx + N_EDGE;

    // ---- workspace partition (256B aligned) ----
    char* p = (char*)d_ws;
    auto alloc = [&](size_t bytes) { char* r = p; p += (bytes + 255) & ~(size_t)255; return (void*)r; };
    int*     cnt       = (int*)    alloc((size_t)N_NODE * 4);
    int*     rowStart  = (int*)    alloc((size_t)(N_NODE + 1) * 4);
    int*     blockSums = (int*)    alloc((size_t)(NB_SCAN + 1) * 4);
    float*   dinv      = (float*)  alloc((size_t)N_NODE * 4);
    float*   alphaT    = (float*)  alloc(64);
    ushort4* h0        = (ushort4*)alloc((size_t)N_NODE * 64);  // bf16 [N][32]
    ushort4* h1        = (ushort4*)alloc((size_t)N_NODE * 64);
    int2*    csr       = (int2*)   alloc((size_t)N_EDGE * 8);
    (void)ws_size; (void)in_sizes; (void)n_in; (void)out_size;

    hipMemsetAsync(cnt, 0, (size_t)N_NODE * 4, stream);

    const int TB = 256;
    int eBlocks = (N_EDGE + TB - 1) / TB;
    int nBlocks = (N_NODE + TB - 1) / TB;

    count_kernel<<<eBlocks, TB, 0, stream>>>(row, cnt, N_EDGE);
    blockscan_kernel<<<NB_SCAN, TB, 0, stream>>>(cnt, rowStart, blockSums, N_NODE);
    scansums_kernel<<<1, 512, 0, stream>>>(blockSums, NB_SCAN);
    addoffs_kernel<<<(N_NODE + 1 + TB - 1) / TB, TB, 0, stream>>>(rowStart, blockSums, N_NODE, NB_SCAN);
    dinv_kernel<<<nBlocks, TB, 0, stream>>>(cnt, dinv, N_NODE);
    scatter_kernel<<<eBlocks, TB, 0, stream>>>(row, col, eattr, rowStart, cnt, dinv, csr, N_EDGE);
    alpha_kernel<<<1, 64, 0, stream>>>(alphas, alphaT);
    copyx_kernel<<<(N_NODE * 8 + TB - 1) / TB, TB, 0, stream>>>((const float4*)x, (float4*)out, h0);

    int spmmBlocks = (N_NODE * 64 + TB - 1) / TB;  // one 64-lane wave per row
    for (int L = 1; L <= DEPTH; ++L) {
        const ushort4* hp = (L & 1) ? h0 : h1;
        ushort4*       hc = (L & 1) ? h1 : h0;
        spmm_kernel<<<spmmBlocks, TB, 0, stream>>>(rowStart, csr, alphaT, L, hp, hc, out);
    }
}